// Round 1
// baseline (62.545 us; speedup 1.0000x reference)
//
#include <hip/hip_runtime.h>

#define BB 4
#define SS 8192
#define DD 1024

// Detect how the boolean `boundaries` array was materialized on device:
// flag 0 = int32 (0/1), 1 = byte bool, 2 = float32 (0.0/1.0).
// Scans the first B*S bytes (valid under all three interpretations).
__global__ void detect_dtype(const unsigned char* __restrict__ b, int* __restrict__ flag) {
    __shared__ int nonbin, misal;
    if (threadIdx.x == 0) { nonbin = 0; misal = 0; }
    __syncthreads();
    int localNon = 0, localMis = 0;
    for (int i = threadIdx.x; i < BB * SS; i += blockDim.x) {
        unsigned char v = b[i];
        if (v > 1) localNon++;
        else if (v == 1 && (i & 3)) localMis++;
    }
    if (localNon) atomicAdd(&nonbin, localNon);
    if (localMis) atomicAdd(&misal, localMis);
    __syncthreads();
    if (threadIdx.x == 0) *flag = nonbin ? 2 : (misal ? 1 : 0);
}

// One block per batch, 1024 threads, 8 elements/thread.
// Builds sel[b][c] = source row index for output chunk c, and writes
// num_tokens[b] (as float) into the output tail.
__global__ __launch_bounds__(1024) void build_sel(const void* __restrict__ bptr,
                                                  const int* __restrict__ flag,
                                                  int* __restrict__ sel,
                                                  float* __restrict__ ntok_out,
                                                  int max_chunks) {
    const int b = blockIdx.x;
    const int t = threadIdx.x;
    const int f = *flag;
    const int base = t * 8;

    unsigned char vals[8];
    int cnt = 0;
    for (int k = 0; k < 8; ++k) {
        const int j = base + k;
        int v;
        if (f == 0)      v = ((const int*)bptr)[b * SS + j] != 0;
        else if (f == 1) v = ((const unsigned char*)bptr)[b * SS + j] != 0;
        else             v = ((const float*)bptr)[b * SS + j] != 0.0f;
        vals[k] = (unsigned char)v;
        cnt += v;
    }

    // Wave-level (64-lane) inclusive scan of per-thread counts.
    const int lane = t & 63;
    const int wave = t >> 6;
    int scan = cnt;
    for (int o = 1; o < 64; o <<= 1) {
        int n = __shfl_up(scan, o, 64);
        if (lane >= o) scan += n;
    }

    __shared__ int waveTot[16];
    __shared__ int waveOff[16];
    __shared__ int total;
    if (lane == 63) waveTot[wave] = scan;
    __syncthreads();
    if (t == 0) {
        int acc = 0;
        for (int w = 0; w < 16; ++w) { waveOff[w] = acc; acc += waveTot[w]; }
        total = acc;
    }
    __syncthreads();

    const int T = total;
    int trueBefore = waveOff[wave] + (scan - cnt);   // exclusive prefix of trues
    int falseBefore = base - trueBefore;             // exclusive prefix of falses

    for (int k = 0; k < 8; ++k) {
        const int j = base + k;
        int dest;
        if (vals[k]) dest = trueBefore++;
        else         dest = T + falseBefore++;
        if (dest < max_chunks) sel[b * max_chunks + dest] = j;
    }
    if (t == 0) ntok_out[b] = (float)T;
}

// One 256-thread block per output row; float4 copy (1024 floats = 256 x 16B).
__global__ __launch_bounds__(256) void gather_rows(const float* __restrict__ x,
                                                   const int* __restrict__ sel,
                                                   float* __restrict__ out,
                                                   int max_chunks) {
    const long long row = blockIdx.x;
    const int b = (int)(row / max_chunks);
    const int j = sel[row];
    const float4* __restrict__ src =
        (const float4*)(x + ((long long)b * SS + (long long)j) * DD);
    float4* __restrict__ dst = (float4*)(out + row * (long long)DD);
    dst[threadIdx.x] = src[threadIdx.x];
}

extern "C" void kernel_launch(void* const* d_in, const int* in_sizes, int n_in,
                              void* d_out, int out_size, void* d_ws, size_t ws_size,
                              hipStream_t stream) {
    const float* x = (const float*)d_in[0];
    const void* bptr = d_in[1];
    float* out = (float*)d_out;

    const int max_chunks = (out_size - BB) / (BB * DD);

    int* flag = (int*)d_ws;
    int* sel = (int*)((char*)d_ws + 256);
    float* ntok = out + (long long)BB * max_chunks * DD;

    detect_dtype<<<1, 256, 0, stream>>>((const unsigned char*)bptr, flag);
    build_sel<<<BB, 1024, 0, stream>>>(bptr, flag, sel, ntok, max_chunks);
    gather_rows<<<BB * max_chunks, 256, 0, stream>>>(x, sel, out, max_chunks);
}

// Round 2
// 21.082 us; speedup vs baseline: 2.9668x; 2.9668x over previous
//
#include <hip/hip_runtime.h>

#define BB 4
#define SS 8192
#define DD 1024

// One block per batch, 1024 threads, 8 boundary elements/thread.
// Fuses: (a) on-device dtype detection of `boundaries` (int32 / byte-bool /
// float32) over the first B*S bytes, (b) stable-partition prefix scan,
// (c) scatter of sel[b][c] = source row index, (d) num_tokens write.
__global__ __launch_bounds__(1024) void build_sel(const void* __restrict__ bptr,
                                                  int* __restrict__ sel,
                                                  float* __restrict__ ntok_out,
                                                  int max_chunks) {
    const int b = blockIdx.x;
    const int t = threadIdx.x;

    // ---- dtype detection (vectorized, block-local) ----
    __shared__ int s_nonbin, s_misal;
    if (t == 0) { s_nonbin = 0; s_misal = 0; }
    __syncthreads();
    {
        const uint4* __restrict__ wp = (const uint4*)bptr;  // (BB*SS)/16 = 2048
        int localNon = 0, localMis = 0;
        for (int i = t; i < (BB * SS) / 16; i += 1024) {
            uint4 w = wp[i];
            unsigned int ws[4] = {w.x, w.y, w.z, w.w};
            #pragma unroll
            for (int q = 0; q < 4; ++q) {
                unsigned int v = ws[q];
                unsigned int b0 = v & 0xFFu, b1 = (v >> 8) & 0xFFu,
                             b2 = (v >> 16) & 0xFFu, b3 = (v >> 24) & 0xFFu;
                if (b0 > 1u || b1 > 1u || b2 > 1u || b3 > 1u) localNon = 1;
                if (b1 == 1u || b2 == 1u || b3 == 1u) localMis = 1;
            }
        }
        if (localNon) atomicAdd(&s_nonbin, 1);
        if (localMis) atomicAdd(&s_misal, 1);
    }
    __syncthreads();
    const int f = s_nonbin ? 2 : (s_misal ? 1 : 0);

    // ---- vectorized boundary read: 8 elements per thread ----
    const int base = t * 8;
    unsigned char vals[8];
    int cnt = 0;
    if (f == 0) {
        const int4* __restrict__ p = (const int4*)((const int*)bptr + b * SS);
        int4 w0 = p[t * 2], w1 = p[t * 2 + 1];
        int vi[8] = {w0.x, w0.y, w0.z, w0.w, w1.x, w1.y, w1.z, w1.w};
        #pragma unroll
        for (int k = 0; k < 8; ++k) { vals[k] = vi[k] != 0; cnt += vals[k]; }
    } else if (f == 1) {
        const uint2* __restrict__ p = (const uint2*)((const unsigned char*)bptr + b * SS);
        uint2 w = p[t];
        unsigned int ws[2] = {w.x, w.y};
        #pragma unroll
        for (int k = 0; k < 8; ++k) {
            vals[k] = ((ws[k >> 2] >> ((k & 3) * 8)) & 0xFFu) != 0u;
            cnt += vals[k];
        }
    } else {
        const float4* __restrict__ p = (const float4*)((const float*)bptr + b * SS);
        float4 w0 = p[t * 2], w1 = p[t * 2 + 1];
        float vf[8] = {w0.x, w0.y, w0.z, w0.w, w1.x, w1.y, w1.z, w1.w};
        #pragma unroll
        for (int k = 0; k < 8; ++k) { vals[k] = vf[k] != 0.0f; cnt += vals[k]; }
    }

    // ---- wave-level (64-lane) inclusive scan of per-thread counts ----
    const int lane = t & 63;
    const int wave = t >> 6;
    int scan = cnt;
    #pragma unroll
    for (int o = 1; o < 64; o <<= 1) {
        int n = __shfl_up(scan, o, 64);
        if (lane >= o) scan += n;
    }

    __shared__ int waveTot[16];
    __shared__ int waveOff[16];
    __shared__ int total;
    if (lane == 63) waveTot[wave] = scan;
    __syncthreads();
    if (t == 0) {
        int acc = 0;
        #pragma unroll
        for (int w = 0; w < 16; ++w) { waveOff[w] = acc; acc += waveTot[w]; }
        total = acc;
    }
    __syncthreads();

    const int T = total;
    int trueBefore = waveOff[wave] + (scan - cnt);   // exclusive prefix of trues
    int falseBefore = base - trueBefore;             // exclusive prefix of falses

    #pragma unroll
    for (int k = 0; k < 8; ++k) {
        const int j = base + k;
        int dest;
        if (vals[k]) dest = trueBefore++;
        else         dest = T + falseBefore++;
        if (dest < max_chunks) sel[b * max_chunks + dest] = j;
    }
    if (t == 0) ntok_out[b] = (float)T;
}

// One wave per output row (4 KB); 256-thread blocks = 4 rows/block.
// Each lane moves 4 x float4, fully coalesced on both sides.
__global__ __launch_bounds__(256) void gather_rows(const float* __restrict__ x,
                                                   const int* __restrict__ sel,
                                                   float* __restrict__ out,
                                                   int max_chunks, int nrows) {
    const int wave = threadIdx.x >> 6;
    const int lane = threadIdx.x & 63;
    const long long row = (long long)blockIdx.x * 4 + wave;
    if (row >= nrows) return;
    const int b = (int)(row / max_chunks);
    const int j = sel[row];
    const float4* __restrict__ src =
        (const float4*)(x + ((long long)b * SS + (long long)j) * DD);
    float4* __restrict__ dst = (float4*)(out + row * (long long)DD);
    #pragma unroll
    for (int k = 0; k < 4; ++k)
        dst[lane + 64 * k] = src[lane + 64 * k];
}

extern "C" void kernel_launch(void* const* d_in, const int* in_sizes, int n_in,
                              void* d_out, int out_size, void* d_ws, size_t ws_size,
                              hipStream_t stream) {
    const float* x = (const float*)d_in[0];
    const void* bptr = d_in[1];
    float* out = (float*)d_out;

    const int max_chunks = (out_size - BB) / (BB * DD);
    const int nrows = BB * max_chunks;

    int* sel = (int*)d_ws;
    float* ntok = out + (long long)nrows * DD;

    build_sel<<<BB, 1024, 0, stream>>>(bptr, sel, ntok, max_chunks);
    gather_rows<<<(nrows + 3) / 4, 256, 0, stream>>>(x, sel, out, max_chunks, nrows);
}